// Round 8
// baseline (688.111 us; speedup 1.0000x reference)
//
#include <hip/hip_runtime.h>

typedef __attribute__((ext_vector_type(4))) float f32x4;
typedef __attribute__((ext_vector_type(8))) short s16x8;
typedef __attribute__((ext_vector_type(4))) unsigned short u16x4;

#define B_    8
#define L_    512
#define LC_   2048
#define EMBD  1024

__device__ __forceinline__ float b2f(unsigned short u) {
  unsigned int i = ((unsigned int)u) << 16;
  float f; __builtin_memcpy(&f, &i, 4); return f;
}
__device__ __forceinline__ unsigned short f2b(float f) {
  unsigned int i; __builtin_memcpy(&i, &f, 4);
  unsigned int r = i + 0x7FFFu + ((i >> 16) & 1u);
  return (unsigned short)(r >> 16);
}

#define GLL16(g, l)                                                         \
  __builtin_amdgcn_global_load_lds(                                         \
      (__attribute__((address_space(1))) void*)(g),                         \
      (__attribute__((address_space(3))) void*)(l), 16, 0, 0)

#define VMCNT6() asm volatile("s_waitcnt vmcnt(6)" ::: "memory")
#define VMCNT0() asm volatile("s_waitcnt vmcnt(0)" ::: "memory")
#define LGKM0()  asm volatile("s_waitcnt lgkmcnt(0)" ::: "memory")

// ---------------------------------------------------------------- converts (all 9 in one launch)
__global__ __launch_bounds__(256) void convert9(
    const float* s0, const float* s1, const float* s2, const float* s3,
    const float* s4, const float* s5, const float* s6, const float* s7,
    const float* s8,
    unsigned short* d0, unsigned short* d1, unsigned short* d2,
    unsigned short* d3, unsigned short* d4, unsigned short* d5,
    unsigned short* d6, unsigned short* d7, unsigned short* d8) {
  int bk = blockIdx.x;
  const float* s; unsigned short* d; int base;
  if      (bk <  2048) { s = s0; d = d0; base = 0; }
  else if (bk <  2112) { s = s1; d = d1; base = 2048; }
  else if (bk <  2176) { s = s2; d = d2; base = 2112; }
  else if (bk <  4224) { s = s3; d = d3; base = 2176; }
  else if (bk <  8320) { s = s4; d = d4; base = 4224; }
  else if (bk < 12416) { s = s5; d = d5; base = 8320; }
  else if (bk < 16512) { s = s6; d = d6; base = 12416; }
  else if (bk < 20608) { s = s7; d = d7; base = 16512; }
  else                 { s = s8; d = d8; base = 20608; }
  int i = (bk - base) * 256 + threadIdx.x;
  float4 v = ((const float4*)s)[i];
  u16x4 o = { f2b(v.x), f2b(v.y), f2b(v.z), f2b(v.w) };
  ((u16x4*)d)[i] = o;
}

// ---------------------------------------------------------------- rmsnorm
__global__ __launch_bounds__(256) void rmsnorm_kernel(
    const float* __restrict__ x, const float* __restrict__ w,
    unsigned short* __restrict__ out) {
  int row = blockIdx.x;
  int tid = threadIdx.x;
  float4 v = ((const float4*)(x + (size_t)row * EMBD))[tid];
  float ss = v.x*v.x + v.y*v.y + v.z*v.z + v.w*v.w;
#pragma unroll
  for (int o = 1; o < 64; o <<= 1) ss += __shfl_xor(ss, o);
  __shared__ float red[4];
  if ((tid & 63) == 0) red[tid >> 6] = ss;
  __syncthreads();
  float tot = red[0] + red[1] + red[2] + red[3];
  float rs = rsqrtf(tot * (1.0f / EMBD) + 1.1920928955078125e-07f);
  float4 wv = ((const float4*)w)[tid];
  u16x4 o = { f2b(v.x*rs*wv.x), f2b(v.y*rs*wv.y), f2b(v.z*rs*wv.z), f2b(v.w*rs*wv.w) };
  ((u16x4*)(out + (size_t)row * EMBD))[tid] = o;
}

// ---------------------------------------------------------------- rope (in-place on [4096][2048] bf16)
__global__ __launch_bounds__(256) void rope_kernel(unsigned short* __restrict__ q) {
  int idx = blockIdx.x * 256 + threadIdx.x;
  int i   = idx & 127;
  int h   = (idx >> 7) & 7;
  int row = idx >> 10;
  int l   = row & (L_ - 1);
  size_t base = (size_t)row * 2048 + h * 256 + i;
  float x1 = b2f(q[base]);
  float x2 = b2f(q[base + 128]);
  float ts  = powf(10000.0f, (float)i * (2.0f / 256.0f));
  float rad = (float)l / ts;
  float s, c;
  sincosf(rad, &s, &c);
  q[base]       = f2b(x1 * c - x2 * s);
  q[base + 128] = f2b(x2 * c + x1 * s);
}

// ---------------------------------------------------------------- silu(g)*u
__global__ __launch_bounds__(256) void act_kernel(
    const unsigned short* __restrict__ g, const unsigned short* __restrict__ u,
    unsigned short* __restrict__ out, int n8) {
  int i = blockIdx.x * 256 + threadIdx.x;
  if (i >= n8) return;
  s16x8 gv = ((const s16x8*)g)[i];
  s16x8 uv = ((const s16x8*)u)[i];
  s16x8 ov;
#pragma unroll
  for (int j = 0; j < 8; ++j) {
    float gf = b2f((unsigned short)gv[j]);
    float uf = b2f((unsigned short)uv[j]);
    float s  = gf / (1.0f + __expf(-gf));
    ov[j] = (short)f2b(s * uf);
  }
  ((s16x8*)out)[i] = ov;
}

// ---------------------------------------------------------------- NT GEMM 128x128 (2-barrier)
template <int ADD_RES, int OUT_BF16>
__global__ __launch_bounds__(256, 2) void gemm_nt(
    const unsigned short* __restrict__ A, const unsigned short* __restrict__ Bw,
    const float* __restrict__ Res, void* __restrict__ C, int M, int N, int K) {
  __shared__ unsigned short As[128 * 64];
  __shared__ unsigned short Bs[128 * 64];
  const int tid = threadIdx.x;
  const int lane = tid & 63, wid = tid >> 6;
  const int l15 = lane & 15, l4 = lane >> 4;
  const int wr = wid >> 1, wc = wid & 1;
  const int m0 = blockIdx.y * 128, n0 = blockIdx.x * 128;

  const f32x4 fz = {0.f, 0.f, 0.f, 0.f};
  f32x4 acc[4][4];
#pragma unroll
  for (int i = 0; i < 4; ++i)
#pragma unroll
    for (int j = 0; j < 4; ++j) acc[i][j] = fz;

  for (int k0 = 0; k0 < K; k0 += 64) {
    __syncthreads();
#pragma unroll
    for (int i = 0; i < 4; ++i) {
      int Li = i * 4096 + tid * 16;
      int row = Li >> 7;
      int kb = (Li & 127) ^ ((row & 7) << 4);
      GLL16((const char*)(A + (size_t)(m0 + row) * K + k0) + kb, (char*)As + Li);
      GLL16((const char*)(Bw + (size_t)(n0 + row) * K + k0) + kb, (char*)Bs + Li);
    }
    __syncthreads();
#pragma unroll
    for (int kk = 0; kk < 2; ++kk) {
      s16x8 af[4], bfr[4];
#pragma unroll
      for (int mi = 0; mi < 4; ++mi) {
        int row = wr * 64 + mi * 16 + l15;
        int kb = (kk * 64 + l4 * 16) ^ ((row & 7) << 4);
        af[mi] = *(const s16x8*)((const char*)As + row * 128 + kb);
      }
#pragma unroll
      for (int ni = 0; ni < 4; ++ni) {
        int row = wc * 64 + ni * 16 + l15;
        int kb = (kk * 64 + l4 * 16) ^ ((row & 7) << 4);
        bfr[ni] = *(const s16x8*)((const char*)Bs + row * 128 + kb);
      }
#pragma unroll
      for (int mi = 0; mi < 4; ++mi)
#pragma unroll
        for (int ni = 0; ni < 4; ++ni)
          acc[mi][ni] = __builtin_amdgcn_mfma_f32_16x16x32_bf16(
              af[mi], bfr[ni], acc[mi][ni], 0, 0, 0);
    }
  }
#pragma unroll
  for (int mi = 0; mi < 4; ++mi) {
#pragma unroll
    for (int r = 0; r < 4; ++r) {
      int grow = m0 + wr * 64 + mi * 16 + l4 * 4 + r;
      size_t base = (size_t)grow * N + n0 + wc * 64 + l15;
#pragma unroll
      for (int ni = 0; ni < 4; ++ni) {
        float v = acc[mi][ni][r];
        size_t idx = base + ni * 16;
        if (ADD_RES) v += Res[idx];
        if (OUT_BF16) ((unsigned short*)C)[idx] = f2b(v);
        else          ((float*)C)[idx] = v;
      }
    }
  }
}

// ---------------------------------------------------------------- NT GEMM 64x128 (512-block grids, 2/CU)
template <int ADD_RES, int OUT_BF16>
__global__ __launch_bounds__(256, 2) void gemm_nt64(
    const unsigned short* __restrict__ A, const unsigned short* __restrict__ Bw,
    const float* __restrict__ Res, void* __restrict__ C, int M, int N, int K) {
  __shared__ unsigned short As[64 * 64];
  __shared__ unsigned short Bs[128 * 64];
  const int tid = threadIdx.x;
  const int lane = tid & 63, wid = tid >> 6;
  const int l15 = lane & 15, l4 = lane >> 4;
  const int wr = wid >> 1, wc = wid & 1;
  const int m0 = blockIdx.y * 64, n0 = blockIdx.x * 128;

  const f32x4 fz = {0.f, 0.f, 0.f, 0.f};
  f32x4 acc[2][4];
#pragma unroll
  for (int i = 0; i < 2; ++i)
#pragma unroll
    for (int j = 0; j < 4; ++j) acc[i][j] = fz;

  for (int k0 = 0; k0 < K; k0 += 64) {
    __syncthreads();
#pragma unroll
    for (int i = 0; i < 2; ++i) {
      int Li = i * 4096 + tid * 16;
      int row = Li >> 7;
      int kb = (Li & 127) ^ ((row & 7) << 4);
      GLL16((const char*)(A + (size_t)(m0 + row) * K + k0) + kb, (char*)As + Li);
    }
#pragma unroll
    for (int i = 0; i < 4; ++i) {
      int Li = i * 4096 + tid * 16;
      int row = Li >> 7;
      int kb = (Li & 127) ^ ((row & 7) << 4);
      GLL16((const char*)(Bw + (size_t)(n0 + row) * K + k0) + kb, (char*)Bs + Li);
    }
    __syncthreads();
#pragma unroll
    for (int kk = 0; kk < 2; ++kk) {
      s16x8 af[2], bfr[4];
#pragma unroll
      for (int mi = 0; mi < 2; ++mi) {
        int row = wr * 32 + mi * 16 + l15;
        int kb = (kk * 64 + l4 * 16) ^ ((row & 7) << 4);
        af[mi] = *(const s16x8*)((const char*)As + row * 128 + kb);
      }
#pragma unroll
      for (int ni = 0; ni < 4; ++ni) {
        int row = wc * 64 + ni * 16 + l15;
        int kb = (kk * 64 + l4 * 16) ^ ((row & 7) << 4);
        bfr[ni] = *(const s16x8*)((const char*)Bs + row * 128 + kb);
      }
#pragma unroll
      for (int mi = 0; mi < 2; ++mi)
#pragma unroll
        for (int ni = 0; ni < 4; ++ni)
          acc[mi][ni] = __builtin_amdgcn_mfma_f32_16x16x32_bf16(
              af[mi], bfr[ni], acc[mi][ni], 0, 0, 0);
    }
  }
#pragma unroll
  for (int mi = 0; mi < 2; ++mi) {
#pragma unroll
    for (int r = 0; r < 4; ++r) {
      int grow = m0 + wr * 32 + mi * 16 + l4 * 4 + r;
      size_t base = (size_t)grow * N + n0 + wc * 64 + l15;
#pragma unroll
      for (int ni = 0; ni < 4; ++ni) {
        float v = acc[mi][ni][r];
        size_t idx = base + ni * 16;
        if (ADD_RES) v += Res[idx];
        if (OUT_BF16) ((unsigned short*)C)[idx] = f2b(v);
        else          ((float*)C)[idx] = v;
      }
    }
  }
}

// ---------------------------------------------------------------- 256x256 8-phase GEMM (T1+T2+T3+T4+T5)
__global__ __launch_bounds__(512, 2) void gemm256(
    const unsigned short* __restrict__ A, const unsigned short* __restrict__ Bw,
    unsigned short* __restrict__ C, int M, int N, int K) {
  extern __shared__ char smem[];
  const int tid = threadIdx.x;
  const int lane = tid & 63;
  const int wid = tid >> 6;
  const int wr = wid >> 2, wc = wid & 3;
  const int l15 = lane & 15, g = lane >> 4;
  int flat = blockIdx.y * 16 + blockIdx.x;
  flat = (flat & 7) * 32 + (flat >> 3);
  const int m0 = (flat >> 4) * 256, n0 = (flat & 15) * 256;
  const int T = K >> 6;
  const int swz = (l15 & 7) << 4;

  auto stage = [&](int t, int mat, int half) {
    char* dst = smem + mat * 65536 + (t & 1) * 32768 + half * 16384;
    const unsigned short* src = (mat ? Bw + (size_t)(n0 + half * 128) * K
                                     : A + (size_t)(m0 + half * 128) * K) + t * 64;
#pragma unroll
    for (int i = 0; i < 2; ++i) {
      int Li = i * 8192 + tid * 16;
      int row = Li >> 7;
      int kb = (Li & 127) ^ ((row & 7) << 4);
      GLL16((const char*)(src + (size_t)row * K) + kb, dst + Li);
    }
  };

  const f32x4 fz = {0.f, 0.f, 0.f, 0.f};
  f32x4 acc[2][2][4][2];
#pragma unroll
  for (int ms = 0; ms < 2; ++ms)
#pragma unroll
    for (int ns = 0; ns < 2; ++ns)
#pragma unroll
      for (int mi = 0; mi < 4; ++mi)
#pragma unroll
        for (int ni = 0; ni < 2; ++ni) acc[ms][ns][mi][ni] = fz;

  stage(0, 1, 0); stage(0, 1, 1); stage(0, 0, 0); stage(0, 0, 1);
  stage(1, 1, 0); stage(1, 1, 1); stage(1, 0, 0);
  VMCNT6();
  __builtin_amdgcn_s_barrier();

  for (int t = 0; t < T; ++t) {
    char* Ab = smem + (t & 1) * 32768 + wr * 16384;
    char* Bb = smem + 65536 + (t & 1) * 32768 + (wc >> 1) * 16384;
    const int bn = (wc & 1) * 64;
    s16x8 a[4][2], b0[2][2], b1[2][2];

#pragma unroll
    for (int mi = 0; mi < 4; ++mi) {
      int row = mi * 16 + l15;
#pragma unroll
      for (int kk = 0; kk < 2; ++kk)
        a[mi][kk] = *(const s16x8*)(Ab + row * 128 + ((kk * 64 + g * 16) ^ swz));
    }
#pragma unroll
    for (int ni = 0; ni < 2; ++ni) {
      int r0 = (bn + ni * 16 + l15) * 128;
      int r1 = (bn + 32 + ni * 16 + l15) * 128;
#pragma unroll
      for (int kk = 0; kk < 2; ++kk) {
        int ko = (kk * 64 + g * 16) ^ swz;
        b0[ni][kk] = *(const s16x8*)(Bb + r0 + ko);
        b1[ni][kk] = *(const s16x8*)(Bb + r1 + ko);
      }
    }
    if (t + 1 < T) stage(t + 1, 0, 1);
    __builtin_amdgcn_s_barrier();
    LGKM0();
    __builtin_amdgcn_sched_barrier(0);
    __builtin_amdgcn_s_setprio(1);
#pragma unroll
    for (int mi = 0; mi < 4; ++mi)
#pragma unroll
      for (int ni = 0; ni < 2; ++ni)
#pragma unroll
        for (int kk = 0; kk < 2; ++kk)
          acc[0][0][mi][ni] = __builtin_amdgcn_mfma_f32_16x16x32_bf16(
              a[mi][kk], b0[ni][kk], acc[0][0][mi][ni], 0, 0, 0);
    __builtin_amdgcn_s_setprio(0);
    __builtin_amdgcn_s_barrier();

    if (t + 2 < T) stage(t + 2, 1, 0);
    __builtin_amdgcn_s_barrier();
    __builtin_amdgcn_s_setprio(1);
#pragma unroll
    for (int mi = 0; mi < 4; ++mi)
#pragma unroll
      for (int ni = 0; ni < 2; ++ni)
#pragma unroll
        for (int kk = 0; kk < 2; ++kk)
          acc[0][1][mi][ni] = __builtin_amdgcn_mfma_f32_16x16x32_bf16(
              a[mi][kk], b1[ni][kk], acc[0][1][mi][ni], 0, 0, 0);
    __builtin_amdgcn_s_setprio(0);
    __builtin_amdgcn_s_barrier();

#pragma unroll
    for (int mi = 0; mi < 4; ++mi) {
      int row = 64 + mi * 16 + l15;
#pragma unroll
      for (int kk = 0; kk < 2; ++kk)
        a[mi][kk] = *(const s16x8*)(Ab + row * 128 + ((kk * 64 + g * 16) ^ swz));
    }
    if (t + 2 < T) stage(t + 2, 1, 1);
    __builtin_amdgcn_s_barrier();
    LGKM0();
    __builtin_amdgcn_sched_barrier(0);
    __builtin_amdgcn_s_setprio(1);
#pragma unroll
    for (int mi = 0; mi < 4; ++mi)
#pragma unroll
      for (int ni = 0; ni < 2; ++ni)
#pragma unroll
        for (int kk = 0; kk < 2; ++kk)
          acc[1][0][mi][ni] = __builtin_amdgcn_mfma_f32_16x16x32_bf16(
              a[mi][kk], b0[ni][kk], acc[1][0][mi][ni], 0, 0, 0);
    __builtin_amdgcn_s_setprio(0);
    __builtin_amdgcn_s_barrier();

    if (t + 2 < T) { stage(t + 2, 0, 0); VMCNT6(); }
    else           { VMCNT0(); }
    __builtin_amdgcn_s_barrier();
    __builtin_amdgcn_s_setprio(1);
#pragma unroll
    for (int mi = 0; mi < 4; ++mi)
#pragma unroll
      for (int ni = 0; ni < 2; ++ni)
#pragma unroll
        for (int kk = 0; kk < 2; ++kk)
          acc[1][1][mi][ni] = __builtin_amdgcn_mfma_f32_16x16x32_bf16(
              a[mi][kk], b1[ni][kk], acc[1][1][mi][ni], 0, 0, 0);
    __builtin_amdgcn_s_setprio(0);
    __builtin_amdgcn_s_barrier();
  }

#pragma unroll
  for (int ms = 0; ms < 2; ++ms)
#pragma unroll
    for (int mi = 0; mi < 4; ++mi)
#pragma unroll
      for (int r = 0; r < 4; ++r) {
        int grow = m0 + wr * 128 + ms * 64 + mi * 16 + g * 4 + r;
        size_t base = (size_t)grow * N + n0 + wc * 64;
#pragma unroll
        for (int ns = 0; ns < 2; ++ns)
#pragma unroll
          for (int ni = 0; ni < 2; ++ni)
            C[base + ns * 32 + ni * 16 + l15] = f2b(acc[ms][ns][mi][ni][r]);
      }
}

// ---------------------------------------------------------------- fused attention (dual-Q-group, split-KV)
// grid (qt=4, h=8, b*2+half=16) = 512 blocks, 256 thr = 4 waves x 32 q-rows.
// Each wave owns TWO 16-q groups (A: wid*32+l15, B: +16) -> every kf/vf LDS
// read feeds 2 MFMAs (halves LDS-pipe reads, the measured bottleneck).
// ~240 VGPR/wave -> 2 waves/SIMD -> 2 blocks/CU (independent barrier domains).
#define SWZV(d) (((((d) & 7) ^ (((d) >> 3) & 7))) << 4)

__global__ __launch_bounds__(256, 2) void attn_kernel(
    const unsigned short* __restrict__ Q,   // [4096][2048] (roped)
    const unsigned short* __restrict__ Kc,  // [B][2048][256]
    const unsigned short* __restrict__ Vc,  // [B][2048][256]
    unsigned short* __restrict__ Op0, unsigned short* __restrict__ Op1,
    float2* __restrict__ Ml0, float2* __restrict__ Ml1) {
  __shared__ unsigned short Ks[64 * 256];
  __shared__ unsigned short Vt[256 * 64];
  const int tid = threadIdx.x;
  const int lane = tid & 63, wid = tid >> 6;
  const int l15 = lane & 15, g = lane >> 4;
  const int qt = blockIdx.x, h = blockIdx.y;
  const int b = blockIdx.z >> 1, half = blockIdx.z & 1;

  const size_t qrowA = (size_t)(b * L_ + qt * 128 + wid * 32 + l15);
  const unsigned short* qpA = Q + qrowA * 2048 + h * 256;
  const unsigned short* qpB = qpA + 16 * 2048;
  s16x8 qfA[8], qfB[8];
#pragma unroll
  for (int kc = 0; kc < 8; ++kc) {
    qfA[kc] = *(const s16x8*)(qpA + kc * 32 + g * 8);
    qfB[kc] = *(const s16x8*)(qpB + kc * 32 + g * 8);
  }

  const f32x4 fz = {0.f, 0.f, 0.f, 0.f};
  f32x4 oaccA[16], oaccB[16];
#pragma unroll
  for (int i = 0; i < 16; ++i) { oaccA[i] = fz; oaccB[i] = fz; }
  float m_runA = -__builtin_inff(), l_runA = 0.f;
  float m_runB = -__builtin_inff(), l_runB = 0.f;

  const unsigned short* Kb = Kc + (size_t)b * LC_ * 256;
  const unsigned short* Vb = Vc + (size_t)b * LC_ * 256;

  const int kt0 = half * 16;
  for (int kt = kt0; kt < kt0 + 16; ++kt) {
    __syncthreads();
    // stage K (64x256) via GLL16, swizzled source
#pragma unroll
    for (int i = 0; i < 8; ++i) {
      int Li = i * 4096 + tid * 16;
      int row = Li >> 9;
      int kb = (Li & 511) ^ ((row & 7) << 4);
      GLL16((const char*)(Kb + (size_t)(kt * 64 + row) * 256) + kb, (char*)Ks + Li);
    }
    // stage V transposed (Vt[d][kv], b32 pair writes, ~2-way conflicts)
#pragma unroll
    for (int p = 0; p < 4; ++p) {
      int id = p * 256 + tid;
      int dgrp = id & 31;
      int kvp = id >> 5;
      int d0 = dgrp * 8, kv0 = kvp * 2;
      const unsigned short* v0p = Vb + (size_t)(kt * 64 + kv0) * 256 + d0;
      s16x8 r0 = *(const s16x8*)v0p;
      s16x8 r1 = *(const s16x8*)(v0p + 256);
#pragma unroll
      for (int j = 0; j < 8; ++j) {
        int d = d0 + j;
        unsigned int val = (unsigned int)(unsigned short)r0[j] |
                           ((unsigned int)(unsigned short)r1[j] << 16);
        *(unsigned int*)((char*)Vt + d * 128 + ((kv0 * 2) ^ SWZV(d))) = val;
      }
    }
    __syncthreads();

    // S^T = K * Q^T for both q-groups; kf read once feeds 2 MFMAs
    f32x4 sA[4], sB[4];
#pragma unroll
    for (int mi = 0; mi < 4; ++mi) { sA[mi] = fz; sB[mi] = fz; }
#pragma unroll
    for (int mi = 0; mi < 4; ++mi) {
      int row = mi * 16 + l15;
      int swz = (row & 7) << 4;
#pragma unroll
      for (int kc = 0; kc < 8; ++kc) {
        s16x8 kf = *(const s16x8*)((const char*)Ks + row * 512 + ((kc * 64 + g * 16) ^ swz));
        sA[mi] = __builtin_amdgcn_mfma_f32_16x16x32_bf16(kf, qfA[kc], sA[mi], 0, 0, 0);
        sB[mi] = __builtin_amdgcn_mfma_f32_16x16x32_bf16(kf, qfB[kc], sB[mi], 0, 0, 0);
      }
    }

    // ---- softmax group A (defer-max THR=8)
    float svA[4][4], svB[4][4];
    unsigned int pkA[4][2], pkB[4][2];
    {
      float mt = -__builtin_inff();
#pragma unroll
      for (int mi = 0; mi < 4; ++mi)
#pragma unroll
        for (int r = 0; r < 4; ++r) {
          float t = sA[mi][r] * 0.0625f;
          svA[mi][r] = t;
          mt = fmaxf(mt, t);
        }
      mt = fmaxf(mt, __shfl_xor(mt, 16));
      mt = fmaxf(mt, __shfl_xor(mt, 32));
      if (!__all(mt <= m_runA + 8.0f)) {
        float mnew = fmaxf(m_runA, mt);
        float alpha = __expf(m_runA - mnew);
        float af4[4];
#pragma unroll
        for (int r = 0; r < 4; ++r) af4[r] = __shfl(alpha, g * 4 + r);
#pragma unroll
        for (int nd = 0; nd < 16; ++nd)
#pragma unroll
          for (int r = 0; r < 4; ++r) oaccA[nd][r] *= af4[r];
        l_runA *= alpha;
        m_runA = mnew;
      }
      float rs = 0.f;
#pragma unroll
      for (int mi = 0; mi < 4; ++mi)
#pragma unroll
        for (int r = 0; r < 4; ++r) {
          float p = __expf(svA[mi][r] - m_runA);
          svA[mi][r] = p;
          rs += p;
        }
      rs += __shfl_xor(rs, 16);
      rs += __shfl_xor(rs, 32);
      l_runA += rs;
#pragma unroll
      for (int ni = 0; ni < 4; ++ni) {
        pkA[ni][0] = (unsigned int)f2b(svA[ni][0]) | ((unsigned int)f2b(svA[ni][1]) << 16);
        pkA[ni][1] = (unsigned int)f2b(svA[ni][2]) | ((unsigned int)f2b(svA[ni][3]) << 16);
      }
    }
    // ---- softmax group B
    {
      float mt = -__builtin_inff();
#pragma unroll
      for (int mi = 0; mi < 4; ++mi)
#pragma unroll
        for (int r = 0; r < 4; ++r) {
          float t = sB[mi][r] * 0.0625f;
          svB[mi][r] = t;
          mt = fmaxf(mt, t);
        }
      mt = fmaxf(mt, __shfl_xor(mt, 16));
      mt = fmaxf(mt, __shfl_xor(mt, 32));
      if (!__all(mt <= m_runB + 8.0f)) {
        float mnew = fmaxf(m_runB, mt);
        float alpha = __expf(m_runB - mnew);
        float af4[4];
#pragma unroll
        for (int r = 0; r < 4; ++r) af4[r] = __shfl(alpha, g * 4 + r);
#pragma unroll
        for (int nd = 0; nd < 16; ++nd)
#pragma unroll
          for (int r = 0; r < 4; ++r) oaccB[nd][r] *= af4[r];
        l_runB *= alpha;
        m_runB = mnew;
      }
      float rs = 0.f;
#pragma unroll
      for (int mi = 0; mi < 4; ++mi)
#pragma unroll
        for (int r = 0; r < 4; ++r) {
          float p = __expf(svB[mi][r] - m_runB);
          svB[mi][r] = p;
          rs += p;
        }
      rs += __shfl_xor(rs, 16);
      rs += __shfl_xor(rs, 32);
      l_runB += rs;
#pragma unroll
      for (int ni = 0; ni < 4; ++ni) {
        pkB[ni][0] = (unsigned int)f2b(svB[ni][0]) | ((unsigned int)f2b(svB[ni][1]) << 16);
        pkB[ni][1] = (unsigned int)f2b(svB[ni][2]) | ((unsigned int)f2b(svB[ni][3]) << 16);
      }
    }

    // ---- PV: vf read once feeds both groups
    int cbase = (g & 1) << 3;
#pragma unroll
    for (int tt = 0; tt < 2; ++tt) {
      unsigned int wA[4], wB[4];
#pragma unroll
      for (int jj = 0; jj < 4; ++jj) {
        int c = cbase + (jj << 1);
        int src = ((c >> 2) << 4) + l15;
        unsigned int raA = __shfl(pkA[2 * tt][jj & 1], src);
        unsigned int rbA = __shfl(pkA[2 * tt + 1][jj & 1], src);
        wA[jj] = (g < 2) ? raA : rbA;
        unsigned int raB = __shfl(pkB[2 * tt][jj & 1], src);
        unsigned int rbB = __shfl(pkB[2 * tt + 1][jj & 1], src);
        wB[jj] = (g < 2) ? raB : rbB;
      }
      union { unsigned int u[4]; s16x8 v; } cvA, cvB;
      cvA.u[0] = wA[0]; cvA.u[1] = wA[1]; cvA.u[2] = wA[2]; cvA.u[3] = wA[3];
      cvB.u[0] = wB[0]; cvB.u[1] = wB[1]; cvB.u[2] = wB[2]; cvB.u[3] = wB[3];
      s16x8 apA = cvA.v, apB = cvB.v;
#pragma unroll
      for (int nd = 0; nd < 16; ++nd) {
        int d = nd * 16 + l15;
        s16x8 vf = *(const s16x8*)((const char*)Vt + d * 128 + ((tt * 64 + g * 16) ^ SWZV(d)));
        oaccA[nd] = __builtin_amdgcn_mfma_f32_16x16x32_bf16(apA, vf, oaccA[nd], 0, 0, 0);
        oaccB[nd] = __builtin_amdgcn_mfma_f32_16x16x32_bf16(apB, vf, oaccB[nd], 0, 0, 0);
      }
    }
  }
  // store normalized partials + (m,l)
  unsigned short* Op = half ? Op1 : Op0;
  float2* Ml = half ? Ml1 : Ml0;
  const size_t orow0A = (size_t)(b * L_ + qt * 128 + wid * 32);
  const size_t orow0B = orow0A + 16;
  float lfA[4], lfB[4];
#pragma unroll
  for (int r = 0; r < 4; ++r) {
    lfA[r] = 1.0f / __shfl(l_runA, g * 4 + r);
    lfB[r] = 1.0f / __shfl(l_runB, g * 4 + r);
  }
#pragma unroll
  for (int r = 0; r < 4; ++r) {
    size_t baseA = (orow0A + g * 4 + r) * 2048 + h * 256 + l15;
    size_t baseB = (orow0B + g * 4 + r) * 2048 + h * 256 + l15;
#pragma unroll
    for (int nd = 0; nd < 16; ++nd) {
      Op[baseA + nd * 16] = f2b(oaccA[nd][r] * lfA[r]);
      Op[baseB + nd * 16] = f2b(oaccB[nd][r] * lfB[r]);
    }
  }
  if (g == 0) {
    Ml[(orow0A + l15) * 8 + h] = make_float2(m_runA, l_runA);
    Ml[(orow0B + l15) * 8 + h] = make_float2(m_runB, l_runB);
  }
}

// ---------------------------------------------------------------- merge split-KV partials
__global__ __launch_bounds__(256) void attn_merge(
    const unsigned short* __restrict__ p0, const unsigned short* __restrict__ p1,
    const float2* __restrict__ ml0, const float2* __restrict__ ml1,
    unsigned short* __restrict__ ctx) {
  int i = blockIdx.x * 256 + threadIdx.x;
  int rowh = i >> 5;
  int dch = i & 31;
  float2 a = ml0[rowh], c = ml1[rowh];
  float M = fmaxf(a.x, c.x);
  float w0 = a.y * __expf(a.x - M), w1 = c.y * __expf(c.x - M);
  float inv = 1.0f / (w0 + w1);
  w0 *= inv; w1 *= inv;
  int row = rowh >> 3, h = rowh & 7;
  size_t off = (size_t)row * 2048 + h * 256 + dch * 8;
  s16x8 v0 = *(const s16x8*)(p0 + off);
  s16x8 v1 = *(const s16x8*)(p1 + off);
  s16x8 o;
#pragma unroll
  for (int j = 0; j < 8; ++j)
    o[j] = (short)f2b(w0 * b2f((unsigned short)v0[j]) + w1 * b2f((unsigned short)v1[j]));
  *(s16x8*)(ctx + off) = o;
}

// ---------------------------------------------------------------- launch
extern "C" void kernel_launch(void* const* d_in, const int* in_sizes, int n_in,
                              void* d_out, int out_size, void* d_ws, size_t ws_size,
                              hipStream_t stream) {
  const float* x   = (const float*)d_in[0];
  const float* tk  = (const float*)d_in[1];
  const float* tv  = (const float*)d_in[2];
  const float* ln1 = (const float*)d_in[3];
  const float* ln2 = (const float*)d_in[4];
  const float* Wq  = (const float*)d_in[5];
  const float* Wk  = (const float*)d_in[6];
  const float* Wv  = (const float*)d_in[7];
  const float* Wo  = (const float*)d_in[8];
  const float* Wg  = (const float*)d_in[9];
  const float* Wu  = (const float*)d_in[10];
  const float* Wd  = (const float*)d_in[11];
  float* out = (float*)d_out;
  char* ws = (char*)d_ws;

  (void)hipFuncSetAttribute((const void*)gemm256,
                            hipFuncAttributeMaxDynamicSharedMemorySize, 131072);

  // workspace layout (126.1 MB, lifetime-based aliasing)
  unsigned short* tk_bf  = (unsigned short*)(ws + 0);
  unsigned short* tv_bf  = (unsigned short*)(ws + 8388608);
  unsigned short* k_bf   = (unsigned short*)(ws + 16777216);
  unsigned short* v_bf   = (unsigned short*)(ws + 25165824);
  unsigned short* g_bf   = (unsigned short*)(ws + 0);         // FFN gate (tk/tv dead)
  unsigned short* op0    = (unsigned short*)(ws + 0);         // attn partial 0 (tk/tv dead)
  unsigned short* q_bf   = (unsigned short*)(ws + 33554432);
  unsigned short* ctx_bf = (unsigned short*)(ws + 50331648);
  unsigned short* u_bf   = (unsigned short*)(ws + 33554432);  // aliases q (dead)
  unsigned short* wq_bf  = (unsigned short*)(ws + 67108864);
  unsigned short* wk_bf  = (unsigned short*)(ws + 71303168);
  unsigned short* wv_bf  = (unsigned short*)(ws + 71434240);
  unsigned short* wo_bf  = (unsigned short*)(ws + 71565312);
  unsigned short* wg_bf  = (unsigned short*)(ws + 75759616);
  unsigned short* wu_bf  = (unsigned short*)(ws + 84148224);
  unsigned short* wd_bf  = (unsigned short*)(ws + 92536832);
  unsigned short* h_bf   = (unsigned short*)(ws + 100925440);
  float2*         ml0    = (float2*)(ws + 100925440);         // h_bf dead during attn
  float2*         ml1    = (float2*)(ws + 100925440 + 262144);
  float*          x2     = (float*)(ws + 109314048);
  unsigned short* op1    = (unsigned short*)(ws + 109314048); // x2 dead until Wo

  dim3 blk(256);
  convert9<<<dim3(24704), blk, 0, stream>>>(
      Wq, Wk, Wv, Wo, Wg, Wu, Wd, tk, tv,
      wq_bf, wk_bf, wv_bf, wo_bf, wg_bf, wu_bf, wd_bf, tk_bf, tv_bf);

  rmsnorm_kernel<<<dim3(4096), blk, 0, stream>>>(x, ln1, h_bf);
  gemm_nt<0, 1><<<dim3(16, 32), blk, 0, stream>>>(h_bf, wq_bf, nullptr, q_bf, 4096, 2048, 1024);
  rope_kernel<<<dim3(16384), blk, 0, stream>>>(q_bf);
  gemm_nt64<0, 1><<<dim3(2, 256), blk, 0, stream>>>(tk_bf, wk_bf, nullptr, k_bf, 16384, 256, 256);
  gemm_nt64<0, 1><<<dim3(2, 256), blk, 0, stream>>>(tv_bf, wv_bf, nullptr, v_bf, 16384, 256, 256);
  attn_kernel<<<dim3(4, 8, 16), dim3(256), 0, stream>>>(q_bf, k_bf, v_bf, op0, op1, ml0, ml1);
  attn_merge<<<dim3(4096), blk, 0, stream>>>(op0, op1, ml0, ml1, ctx_bf);
  gemm_nt64<1, 0><<<dim3(8, 64), blk, 0, stream>>>(ctx_bf, wo_bf, x, x2, 4096, 1024, 2048);
  rmsnorm_kernel<<<dim3(4096), blk, 0, stream>>>(x2, ln2, h_bf);
  gemm256<<<dim3(16, 16), dim3(512), 131072, stream>>>(h_bf, wg_bf, g_bf, 4096, 4096, 1024);
  gemm256<<<dim3(16, 16), dim3(512), 131072, stream>>>(h_bf, wu_bf, u_bf, 4096, 4096, 1024);
  act_kernel<<<dim3(8192), blk, 0, stream>>>(g_bf, u_bf, g_bf, 2097152);
  gemm_nt64<1, 0><<<dim3(8, 64), blk, 0, stream>>>(g_bf, wd_bf, x2, out, 4096, 1024, 4096);
}

// Round 9
// 400.418 us; speedup vs baseline: 1.7185x; 1.7185x over previous
//
#include <hip/hip_runtime.h>

typedef __attribute__((ext_vector_type(4))) float f32x4;
typedef __attribute__((ext_vector_type(8))) short s16x8;
typedef __attribute__((ext_vector_type(4))) unsigned short u16x4;

#define B_    8
#define L_    512
#define LC_   2048
#define EMBD  1024

__device__ __forceinline__ float b2f(unsigned short u) {
  unsigned int i = ((unsigned int)u) << 16;
  float f; __builtin_memcpy(&f, &i, 4); return f;
}
__device__ __forceinline__ unsigned short f2b(float f) {
  unsigned int i; __builtin_memcpy(&i, &f, 4);
  unsigned int r = i + 0x7FFFu + ((i >> 16) & 1u);
  return (unsigned short)(r >> 16);
}

#define GLL16(g, l)                                                         \
  __builtin_amdgcn_global_load_lds(                                         \
      (__attribute__((address_space(1))) void*)(g),                         \
      (__attribute__((address_space(3))) void*)(l), 16, 0, 0)

#define VMCNT6() asm volatile("s_waitcnt vmcnt(6)" ::: "memory")
#define VMCNT0() asm volatile("s_waitcnt vmcnt(0)" ::: "memory")
#define LGKM0()  asm volatile("s_waitcnt lgkmcnt(0)" ::: "memory")

// ---------------------------------------------------------------- converts (all 9 in one launch)
__global__ __launch_bounds__(256) void convert9(
    const float* s0, const float* s1, const float* s2, const float* s3,
    const float* s4, const float* s5, const float* s6, const float* s7,
    const float* s8,
    unsigned short* d0, unsigned short* d1, unsigned short* d2,
    unsigned short* d3, unsigned short* d4, unsigned short* d5,
    unsigned short* d6, unsigned short* d7, unsigned short* d8) {
  int bk = blockIdx.x;
  const float* s; unsigned short* d; int base;
  if      (bk <  2048) { s = s0; d = d0; base = 0; }
  else if (bk <  2112) { s = s1; d = d1; base = 2048; }
  else if (bk <  2176) { s = s2; d = d2; base = 2112; }
  else if (bk <  4224) { s = s3; d = d3; base = 2176; }
  else if (bk <  8320) { s = s4; d = d4; base = 4224; }
  else if (bk < 12416) { s = s5; d = d5; base = 8320; }
  else if (bk < 16512) { s = s6; d = d6; base = 12416; }
  else if (bk < 20608) { s = s7; d = d7; base = 16512; }
  else                 { s = s8; d = d8; base = 20608; }
  int i = (bk - base) * 256 + threadIdx.x;
  float4 v = ((const float4*)s)[i];
  u16x4 o = { f2b(v.x), f2b(v.y), f2b(v.z), f2b(v.w) };
  ((u16x4*)d)[i] = o;
}

// ---------------------------------------------------------------- rmsnorm
__global__ __launch_bounds__(256) void rmsnorm_kernel(
    const float* __restrict__ x, const float* __restrict__ w,
    unsigned short* __restrict__ out) {
  int row = blockIdx.x;
  int tid = threadIdx.x;
  float4 v = ((const float4*)(x + (size_t)row * EMBD))[tid];
  float ss = v.x*v.x + v.y*v.y + v.z*v.z + v.w*v.w;
#pragma unroll
  for (int o = 1; o < 64; o <<= 1) ss += __shfl_xor(ss, o);
  __shared__ float red[4];
  if ((tid & 63) == 0) red[tid >> 6] = ss;
  __syncthreads();
  float tot = red[0] + red[1] + red[2] + red[3];
  float rs = rsqrtf(tot * (1.0f / EMBD) + 1.1920928955078125e-07f);
  float4 wv = ((const float4*)w)[tid];
  u16x4 o = { f2b(v.x*rs*wv.x), f2b(v.y*rs*wv.y), f2b(v.z*rs*wv.z), f2b(v.w*rs*wv.w) };
  ((u16x4*)(out + (size_t)row * EMBD))[tid] = o;
}

// ---------------------------------------------------------------- rope (in-place on [4096][2048] bf16)
__global__ __launch_bounds__(256) void rope_kernel(unsigned short* __restrict__ q) {
  int idx = blockIdx.x * 256 + threadIdx.x;
  int i   = idx & 127;
  int h   = (idx >> 7) & 7;
  int row = idx >> 10;
  int l   = row & (L_ - 1);
  size_t base = (size_t)row * 2048 + h * 256 + i;
  float x1 = b2f(q[base]);
  float x2 = b2f(q[base + 128]);
  float ts  = powf(10000.0f, (float)i * (2.0f / 256.0f));
  float rad = (float)l / ts;
  float s, c;
  sincosf(rad, &s, &c);
  q[base]       = f2b(x1 * c - x2 * s);
  q[base + 128] = f2b(x2 * c + x1 * s);
}

// ---------------------------------------------------------------- NT GEMM 128x128 (2-barrier)
template <int ADD_RES, int OUT_BF16>
__global__ __launch_bounds__(256, 2) void gemm_nt(
    const unsigned short* __restrict__ A, const unsigned short* __restrict__ Bw,
    const float* __restrict__ Res, void* __restrict__ C, int M, int N, int K) {
  __shared__ unsigned short As[128 * 64];
  __shared__ unsigned short Bs[128 * 64];
  const int tid = threadIdx.x;
  const int lane = tid & 63, wid = tid >> 6;
  const int l15 = lane & 15, l4 = lane >> 4;
  const int wr = wid >> 1, wc = wid & 1;
  const int m0 = blockIdx.y * 128, n0 = blockIdx.x * 128;

  const f32x4 fz = {0.f, 0.f, 0.f, 0.f};
  f32x4 acc[4][4];
#pragma unroll
  for (int i = 0; i < 4; ++i)
#pragma unroll
    for (int j = 0; j < 4; ++j) acc[i][j] = fz;

  for (int k0 = 0; k0 < K; k0 += 64) {
    __syncthreads();
#pragma unroll
    for (int i = 0; i < 4; ++i) {
      int Li = i * 4096 + tid * 16;
      int row = Li >> 7;
      int kb = (Li & 127) ^ ((row & 7) << 4);
      GLL16((const char*)(A + (size_t)(m0 + row) * K + k0) + kb, (char*)As + Li);
      GLL16((const char*)(Bw + (size_t)(n0 + row) * K + k0) + kb, (char*)Bs + Li);
    }
    __syncthreads();
#pragma unroll
    for (int kk = 0; kk < 2; ++kk) {
      s16x8 af[4], bfr[4];
#pragma unroll
      for (int mi = 0; mi < 4; ++mi) {
        int row = wr * 64 + mi * 16 + l15;
        int kb = (kk * 64 + l4 * 16) ^ ((row & 7) << 4);
        af[mi] = *(const s16x8*)((const char*)As + row * 128 + kb);
      }
#pragma unroll
      for (int ni = 0; ni < 4; ++ni) {
        int row = wc * 64 + ni * 16 + l15;
        int kb = (kk * 64 + l4 * 16) ^ ((row & 7) << 4);
        bfr[ni] = *(const s16x8*)((const char*)Bs + row * 128 + kb);
      }
#pragma unroll
      for (int mi = 0; mi < 4; ++mi)
#pragma unroll
        for (int ni = 0; ni < 4; ++ni)
          acc[mi][ni] = __builtin_amdgcn_mfma_f32_16x16x32_bf16(
              af[mi], bfr[ni], acc[mi][ni], 0, 0, 0);
    }
  }
#pragma unroll
  for (int mi = 0; mi < 4; ++mi) {
#pragma unroll
    for (int r = 0; r < 4; ++r) {
      int grow = m0 + wr * 64 + mi * 16 + l4 * 4 + r;
      size_t base = (size_t)grow * N + n0 + wc * 64 + l15;
#pragma unroll
      for (int ni = 0; ni < 4; ++ni) {
        float v = acc[mi][ni][r];
        size_t idx = base + ni * 16;
        if (ADD_RES) v += Res[idx];
        if (OUT_BF16) ((unsigned short*)C)[idx] = f2b(v);
        else          ((float*)C)[idx] = v;
      }
    }
  }
}

// ---------------------------------------------------------------- NT GEMM 64x128 (512-block grids, 2/CU)
template <int ADD_RES, int OUT_BF16>
__global__ __launch_bounds__(256, 2) void gemm_nt64(
    const unsigned short* __restrict__ A, const unsigned short* __restrict__ Bw,
    const float* __restrict__ Res, void* __restrict__ C, int M, int N, int K) {
  __shared__ unsigned short As[64 * 64];
  __shared__ unsigned short Bs[128 * 64];
  const int tid = threadIdx.x;
  const int lane = tid & 63, wid = tid >> 6;
  const int l15 = lane & 15, l4 = lane >> 4;
  const int wr = wid >> 1, wc = wid & 1;
  const int m0 = blockIdx.y * 64, n0 = blockIdx.x * 128;

  const f32x4 fz = {0.f, 0.f, 0.f, 0.f};
  f32x4 acc[2][4];
#pragma unroll
  for (int i = 0; i < 2; ++i)
#pragma unroll
    for (int j = 0; j < 4; ++j) acc[i][j] = fz;

  for (int k0 = 0; k0 < K; k0 += 64) {
    __syncthreads();
#pragma unroll
    for (int i = 0; i < 2; ++i) {
      int Li = i * 4096 + tid * 16;
      int row = Li >> 7;
      int kb = (Li & 127) ^ ((row & 7) << 4);
      GLL16((const char*)(A + (size_t)(m0 + row) * K + k0) + kb, (char*)As + Li);
    }
#pragma unroll
    for (int i = 0; i < 4; ++i) {
      int Li = i * 4096 + tid * 16;
      int row = Li >> 7;
      int kb = (Li & 127) ^ ((row & 7) << 4);
      GLL16((const char*)(Bw + (size_t)(n0 + row) * K + k0) + kb, (char*)Bs + Li);
    }
    __syncthreads();
#pragma unroll
    for (int kk = 0; kk < 2; ++kk) {
      s16x8 af[2], bfr[4];
#pragma unroll
      for (int mi = 0; mi < 2; ++mi) {
        int row = wr * 32 + mi * 16 + l15;
        int kb = (kk * 64 + l4 * 16) ^ ((row & 7) << 4);
        af[mi] = *(const s16x8*)((const char*)As + row * 128 + kb);
      }
#pragma unroll
      for (int ni = 0; ni < 4; ++ni) {
        int row = wc * 64 + ni * 16 + l15;
        int kb = (kk * 64 + l4 * 16) ^ ((row & 7) << 4);
        bfr[ni] = *(const s16x8*)((const char*)Bs + row * 128 + kb);
      }
#pragma unroll
      for (int mi = 0; mi < 2; ++mi)
#pragma unroll
        for (int ni = 0; ni < 4; ++ni)
          acc[mi][ni] = __builtin_amdgcn_mfma_f32_16x16x32_bf16(
              af[mi], bfr[ni], acc[mi][ni], 0, 0, 0);
    }
  }
#pragma unroll
  for (int mi = 0; mi < 2; ++mi) {
#pragma unroll
    for (int r = 0; r < 4; ++r) {
      int grow = m0 + wr * 32 + mi * 16 + l4 * 4 + r;
      size_t base = (size_t)grow * N + n0 + wc * 64 + l15;
#pragma unroll
      for (int ni = 0; ni < 4; ++ni) {
        float v = acc[mi][ni][r];
        size_t idx = base + ni * 16;
        if (ADD_RES) v += Res[idx];
        if (OUT_BF16) ((unsigned short*)C)[idx] = f2b(v);
        else          ((float*)C)[idx] = v;
      }
    }
  }
}

// ---------------------------------------------------------------- 256x256 8-phase GEMM (T1..T5; optional fused silu(g)*acc)
template <int SWIGLU>
__global__ __launch_bounds__(512, 2) void gemm256(
    const unsigned short* __restrict__ A, const unsigned short* __restrict__ Bw,
    const unsigned short* __restrict__ G, unsigned short* __restrict__ C,
    int M, int N, int K) {
  extern __shared__ char smem[];
  const int tid = threadIdx.x;
  const int lane = tid & 63;
  const int wid = tid >> 6;
  const int wr = wid >> 2, wc = wid & 3;
  const int l15 = lane & 15, g = lane >> 4;
  int flat = blockIdx.y * 16 + blockIdx.x;
  flat = (flat & 7) * 32 + (flat >> 3);
  const int m0 = (flat >> 4) * 256, n0 = (flat & 15) * 256;
  const int T = K >> 6;
  const int swz = (l15 & 7) << 4;

  auto stage = [&](int t, int mat, int half) {
    char* dst = smem + mat * 65536 + (t & 1) * 32768 + half * 16384;
    const unsigned short* src = (mat ? Bw + (size_t)(n0 + half * 128) * K
                                     : A + (size_t)(m0 + half * 128) * K) + t * 64;
#pragma unroll
    for (int i = 0; i < 2; ++i) {
      int Li = i * 8192 + tid * 16;
      int row = Li >> 7;
      int kb = (Li & 127) ^ ((row & 7) << 4);
      GLL16((const char*)(src + (size_t)row * K) + kb, dst + Li);
    }
  };

  const f32x4 fz = {0.f, 0.f, 0.f, 0.f};
  f32x4 acc[2][2][4][2];
#pragma unroll
  for (int ms = 0; ms < 2; ++ms)
#pragma unroll
    for (int ns = 0; ns < 2; ++ns)
#pragma unroll
      for (int mi = 0; mi < 4; ++mi)
#pragma unroll
        for (int ni = 0; ni < 2; ++ni) acc[ms][ns][mi][ni] = fz;

  stage(0, 1, 0); stage(0, 1, 1); stage(0, 0, 0); stage(0, 0, 1);
  stage(1, 1, 0); stage(1, 1, 1); stage(1, 0, 0);
  VMCNT6();
  __builtin_amdgcn_s_barrier();

  for (int t = 0; t < T; ++t) {
    char* Ab = smem + (t & 1) * 32768 + wr * 16384;
    char* Bb = smem + 65536 + (t & 1) * 32768 + (wc >> 1) * 16384;
    const int bn = (wc & 1) * 64;
    s16x8 a[4][2], b0[2][2], b1[2][2];

#pragma unroll
    for (int mi = 0; mi < 4; ++mi) {
      int row = mi * 16 + l15;
#pragma unroll
      for (int kk = 0; kk < 2; ++kk)
        a[mi][kk] = *(const s16x8*)(Ab + row * 128 + ((kk * 64 + g * 16) ^ swz));
    }
#pragma unroll
    for (int ni = 0; ni < 2; ++ni) {
      int r0 = (bn + ni * 16 + l15) * 128;
      int r1 = (bn + 32 + ni * 16 + l15) * 128;
#pragma unroll
      for (int kk = 0; kk < 2; ++kk) {
        int ko = (kk * 64 + g * 16) ^ swz;
        b0[ni][kk] = *(const s16x8*)(Bb + r0 + ko);
        b1[ni][kk] = *(const s16x8*)(Bb + r1 + ko);
      }
    }
    if (t + 1 < T) stage(t + 1, 0, 1);
    __builtin_amdgcn_s_barrier();
    LGKM0();
    __builtin_amdgcn_sched_barrier(0);
    __builtin_amdgcn_s_setprio(1);
#pragma unroll
    for (int mi = 0; mi < 4; ++mi)
#pragma unroll
      for (int ni = 0; ni < 2; ++ni)
#pragma unroll
        for (int kk = 0; kk < 2; ++kk)
          acc[0][0][mi][ni] = __builtin_amdgcn_mfma_f32_16x16x32_bf16(
              a[mi][kk], b0[ni][kk], acc[0][0][mi][ni], 0, 0, 0);
    __builtin_amdgcn_s_setprio(0);
    __builtin_amdgcn_s_barrier();

    if (t + 2 < T) stage(t + 2, 1, 0);
    __builtin_amdgcn_s_barrier();
    __builtin_amdgcn_s_setprio(1);
#pragma unroll
    for (int mi = 0; mi < 4; ++mi)
#pragma unroll
      for (int ni = 0; ni < 2; ++ni)
#pragma unroll
        for (int kk = 0; kk < 2; ++kk)
          acc[0][1][mi][ni] = __builtin_amdgcn_mfma_f32_16x16x32_bf16(
              a[mi][kk], b1[ni][kk], acc[0][1][mi][ni], 0, 0, 0);
    __builtin_amdgcn_s_setprio(0);
    __builtin_amdgcn_s_barrier();

#pragma unroll
    for (int mi = 0; mi < 4; ++mi) {
      int row = 64 + mi * 16 + l15;
#pragma unroll
      for (int kk = 0; kk < 2; ++kk)
        a[mi][kk] = *(const s16x8*)(Ab + row * 128 + ((kk * 64 + g * 16) ^ swz));
    }
    if (t + 2 < T) stage(t + 2, 1, 1);
    __builtin_amdgcn_s_barrier();
    LGKM0();
    __builtin_amdgcn_sched_barrier(0);
    __builtin_amdgcn_s_setprio(1);
#pragma unroll
    for (int mi = 0; mi < 4; ++mi)
#pragma unroll
      for (int ni = 0; ni < 2; ++ni)
#pragma unroll
        for (int kk = 0; kk < 2; ++kk)
          acc[1][0][mi][ni] = __builtin_amdgcn_mfma_f32_16x16x32_bf16(
              a[mi][kk], b0[ni][kk], acc[1][0][mi][ni], 0, 0, 0);
    __builtin_amdgcn_s_setprio(0);
    __builtin_amdgcn_s_barrier();

    if (t + 2 < T) { stage(t + 2, 0, 0); VMCNT6(); }
    else           { VMCNT0(); }
    __builtin_amdgcn_s_barrier();
    __builtin_amdgcn_s_setprio(1);
#pragma unroll
    for (int mi = 0; mi < 4; ++mi)
#pragma unroll
      for (int ni = 0; ni < 2; ++ni)
#pragma unroll
        for (int kk = 0; kk < 2; ++kk)
          acc[1][1][mi][ni] = __builtin_amdgcn_mfma_f32_16x16x32_bf16(
              a[mi][kk], b1[ni][kk], acc[1][1][mi][ni], 0, 0, 0);
    __builtin_amdgcn_s_setprio(0);
    __builtin_amdgcn_s_barrier();
  }

#pragma unroll
  for (int ms = 0; ms < 2; ++ms)
#pragma unroll
    for (int mi = 0; mi < 4; ++mi)
#pragma unroll
      for (int r = 0; r < 4; ++r) {
        int grow = m0 + wr * 128 + ms * 64 + mi * 16 + g * 4 + r;
        size_t base = (size_t)grow * N + n0 + wc * 64;
#pragma unroll
        for (int ns = 0; ns < 2; ++ns)
#pragma unroll
          for (int ni = 0; ni < 2; ++ni) {
            size_t idx = base + ns * 32 + ni * 16 + l15;
            float v = acc[ms][ns][mi][ni][r];
            if (SWIGLU) {
              float gf = b2f(G[idx]);
              v *= gf / (1.0f + __expf(-gf));
            }
            C[idx] = f2b(v);
          }
      }
}

// ---------------------------------------------------------------- fused attention (split-KV + LDS dbuf)
// grid (qt=4, h=8, b*2+half=16), 512 thr (8 waves x 16 q-rows), 16 KV tiles/blk.
// Staging addressing identical to R7 (known-good); only dbuf'd: issue K GLL16 +
// V global loads for t+1 before compute(t); vmcnt0 + V-write after; 1 barrier.
#define SWZV(d) (((((d) & 7) ^ (((d) >> 3) & 7))) << 4)

__global__ __launch_bounds__(512, 2) void attn_kernel(
    const unsigned short* __restrict__ Q,   // [4096][2048] (roped)
    const unsigned short* __restrict__ Kc,  // [B][2048][256]
    const unsigned short* __restrict__ Vc,  // [B][2048][256]
    unsigned short* __restrict__ Op0, unsigned short* __restrict__ Op1,
    float2* __restrict__ Ml0, float2* __restrict__ Ml1) {
  extern __shared__ char ats[];   // Ks[2] 2x32KB | Vt[2] 2x32KB = 128KB
  const int tid = threadIdx.x;
  const int lane = tid & 63, wid = tid >> 6;
  const int l15 = lane & 15, g = lane >> 4;
  const int qt = blockIdx.x, h = blockIdx.y;
  const int b = blockIdx.z >> 1, half = blockIdx.z & 1;

  const size_t qrow = (size_t)(b * L_ + qt * 128 + wid * 16 + l15);
  const unsigned short* qp = Q + qrow * 2048 + h * 256;
  s16x8 qf[8];
#pragma unroll
  for (int kc = 0; kc < 8; ++kc) qf[kc] = *(const s16x8*)(qp + kc * 32 + g * 8);

  const f32x4 fz = {0.f, 0.f, 0.f, 0.f};
  f32x4 oacc[16];
#pragma unroll
  for (int i = 0; i < 16; ++i) oacc[i] = fz;
  float m_run = -__builtin_inff(), l_run = 0.f;

  const unsigned short* Kb = Kc + (size_t)b * LC_ * 256;
  const unsigned short* Vb = Vc + (size_t)b * LC_ * 256;

  // staging helpers (addressing byte-identical to R7)
  auto stageK = [&](int kt, char* dstK) {
#pragma unroll
    for (int i = 0; i < 4; ++i) {
      int Li = i * 8192 + tid * 16;
      int row = Li >> 9;
      int kb = (Li & 511) ^ ((row & 7) << 4);
      GLL16((const char*)(Kb + (size_t)(kt * 64 + row) * 256) + kb, dstK + Li);
    }
  };
  s16x8 vr[2][2];
  auto loadV = [&](int kt) {
#pragma unroll
    for (int p = 0; p < 2; ++p) {
      int id = p * 512 + tid;
      int dgrp = id & 31, kvp = id >> 5;
      const unsigned short* v0p = Vb + (size_t)(kt * 64 + kvp * 2) * 256 + dgrp * 8;
      vr[p][0] = *(const s16x8*)v0p;
      vr[p][1] = *(const s16x8*)(v0p + 256);
    }
  };
  auto writeV = [&](char* dstV) {
#pragma unroll
    for (int p = 0; p < 2; ++p) {
      int id = p * 512 + tid;
      int dgrp = id & 31, kvp = id >> 5;
      int d0 = dgrp * 8, kv0 = kvp * 2;
#pragma unroll
      for (int j = 0; j < 8; ++j) {
        int d = d0 + j;
        unsigned int val = (unsigned int)(unsigned short)vr[p][0][j] |
                           ((unsigned int)(unsigned short)vr[p][1][j] << 16);
        *(unsigned int*)(dstV + d * 128 + ((kv0 * 2) ^ SWZV(d))) = val;
      }
    }
  };

  const int kt0 = half * 16, ktE = kt0 + 16;
  // prologue: tile kt0 -> buffer 0
  stageK(kt0, ats);
  loadV(kt0);
  VMCNT0();
  writeV(ats + 65536);
  __syncthreads();

  for (int kt = kt0; kt < ktE; ++kt) {
    const int cur = (kt - kt0) & 1, nxt = cur ^ 1;
    char* KsB = ats + cur * 32768;
    char* VtB = ats + 65536 + cur * 32768;
    const bool more = (kt + 1 < ktE);
    if (more) { stageK(kt + 1, ats + nxt * 32768); loadV(kt + 1); }

    // S^T = K * Q^T
    f32x4 sacc[4];
#pragma unroll
    for (int mi = 0; mi < 4; ++mi) sacc[mi] = fz;
#pragma unroll
    for (int mi = 0; mi < 4; ++mi) {
      int row = mi * 16 + l15;
      int swz = (row & 7) << 4;
#pragma unroll
      for (int kc = 0; kc < 8; ++kc) {
        s16x8 kf = *(const s16x8*)(KsB + row * 512 + ((kc * 64 + g * 16) ^ swz));
        sacc[mi] = __builtin_amdgcn_mfma_f32_16x16x32_bf16(kf, qf[kc], sacc[mi], 0, 0, 0);
      }
    }
    // online softmax with defer-max (THR=8)
    float sv[4][4];
    float mt = -__builtin_inff();
#pragma unroll
    for (int mi = 0; mi < 4; ++mi)
#pragma unroll
      for (int r = 0; r < 4; ++r) {
        float t = sacc[mi][r] * 0.0625f;
        sv[mi][r] = t;
        mt = fmaxf(mt, t);
      }
    mt = fmaxf(mt, __shfl_xor(mt, 16));
    mt = fmaxf(mt, __shfl_xor(mt, 32));
    if (!__all(mt <= m_run + 8.0f)) {
      float mnew = fmaxf(m_run, mt);
      float alpha = __expf(m_run - mnew);
      float af4[4];
#pragma unroll
      for (int r = 0; r < 4; ++r) af4[r] = __shfl(alpha, g * 4 + r);
#pragma unroll
      for (int nd = 0; nd < 16; ++nd)
#pragma unroll
        for (int r = 0; r < 4; ++r) oacc[nd][r] *= af4[r];
      l_run *= alpha;
      m_run = mnew;
    }
    float rs = 0.f;
#pragma unroll
    for (int mi = 0; mi < 4; ++mi)
#pragma unroll
      for (int r = 0; r < 4; ++r) {
        float p = __expf(sv[mi][r] - m_run);
        sv[mi][r] = p;
        rs += p;
      }
    rs += __shfl_xor(rs, 16);
    rs += __shfl_xor(rs, 32);
    l_run += rs;
    // pack P pairs to bf16 and redistribute into A-frag layout
    unsigned int pk[4][2];
#pragma unroll
    for (int ni = 0; ni < 4; ++ni) {
      pk[ni][0] = (unsigned int)f2b(sv[ni][0]) | ((unsigned int)f2b(sv[ni][1]) << 16);
      pk[ni][1] = (unsigned int)f2b(sv[ni][2]) | ((unsigned int)f2b(sv[ni][3]) << 16);
    }
    int cbase = (g & 1) << 3;
#pragma unroll
    for (int tt = 0; tt < 2; ++tt) {
      unsigned int w[4];
#pragma unroll
      for (int jj = 0; jj < 4; ++jj) {
        int c = cbase + (jj << 1);
        int src = ((c >> 2) << 4) + l15;
        unsigned int ra = __shfl(pk[2 * tt][jj & 1], src);
        unsigned int rb = __shfl(pk[2 * tt + 1][jj & 1], src);
        w[jj] = (g < 2) ? ra : rb;
      }
      union { unsigned int u[4]; s16x8 v; } cvt;
      cvt.u[0] = w[0]; cvt.u[1] = w[1]; cvt.u[2] = w[2]; cvt.u[3] = w[3];
      s16x8 ap = cvt.v;
#pragma unroll
      for (int nd = 0; nd < 16; ++nd) {
        int d = nd * 16 + l15;
        s16x8 vf = *(const s16x8*)(VtB + d * 128 + ((tt * 64 + g * 16) ^ SWZV(d)));
        oacc[nd] = __builtin_amdgcn_mfma_f32_16x16x32_bf16(ap, vf, oacc[nd], 0, 0, 0);
      }
    }

    if (more) { VMCNT0(); writeV(ats + 65536 + nxt * 32768); }
    __syncthreads();
  }
  // store normalized partial + (m,l)
  unsigned short* Op = half ? Op1 : Op0;
  float2* Ml = half ? Ml1 : Ml0;
  float lf[4];
#pragma unroll
  for (int r = 0; r < 4; ++r) lf[r] = 1.0f / __shfl(l_run, g * 4 + r);
  const size_t orow0 = (size_t)(b * L_ + qt * 128 + wid * 16);
#pragma unroll
  for (int r = 0; r < 4; ++r) {
    size_t base = (orow0 + g * 4 + r) * 2048 + h * 256 + l15;
#pragma unroll
    for (int nd = 0; nd < 16; ++nd)
      Op[base + nd * 16] = f2b(oacc[nd][r] * lf[r]);
  }
  if (g == 0) Ml[(orow0 + l15) * 8 + h] = make_float2(m_run, l_run);
}

// ---------------------------------------------------------------- merge split-KV partials
__global__ __launch_bounds__(256) void attn_merge(
    const unsigned short* __restrict__ p0, const unsigned short* __restrict__ p1,
    const float2* __restrict__ ml0, const float2* __restrict__ ml1,
    unsigned short* __restrict__ ctx) {
  int i = blockIdx.x * 256 + threadIdx.x;
  int rowh = i >> 5;
  int dch = i & 31;
  float2 a = ml0[rowh], c = ml1[rowh];
  float M = fmaxf(a.x, c.x);
  float w0 = a.y * __expf(a.x - M), w1 = c.y * __expf(c.x - M);
  float inv = 1.0f / (w0 + w1);
  w0 *= inv; w1 *= inv;
  int row = rowh >> 3, h = rowh & 7;
  size_t off = (size_t)row * 2048 + h * 256 + dch * 8;
  s16x8 v0 = *(const s16x8*)(p0 + off);
  s16x8 v1 = *(const s16x8*)(p1 + off);
  s16x8 o;
#pragma unroll
  for (int j = 0; j < 8; ++j)
    o[j] = (short)f2b(w0 * b2f((unsigned short)v0[j]) + w1 * b2f((unsigned short)v1[j]));
  *(s16x8*)(ctx + off) = o;
}

// ---------------------------------------------------------------- launch
extern "C" void kernel_launch(void* const* d_in, const int* in_sizes, int n_in,
                              void* d_out, int out_size, void* d_ws, size_t ws_size,
                              hipStream_t stream) {
  const float* x   = (const float*)d_in[0];
  const float* tk  = (const float*)d_in[1];
  const float* tv  = (const float*)d_in[2];
  const float* ln1 = (const float*)d_in[3];
  const float* ln2 = (const float*)d_in[4];
  const float* Wq  = (const float*)d_in[5];
  const float* Wk  = (const float*)d_in[6];
  const float* Wv  = (const float*)d_in[7];
  const float* Wo  = (const float*)d_in[8];
  const float* Wg  = (const float*)d_in[9];
  const float* Wu  = (const float*)d_in[10];
  const float* Wd  = (const float*)d_in[11];
  float* out = (float*)d_out;
  char* ws = (char*)d_ws;

  (void)hipFuncSetAttribute((const void*)gemm256<0>,
                            hipFuncAttributeMaxDynamicSharedMemorySize, 131072);
  (void)hipFuncSetAttribute((const void*)gemm256<1>,
                            hipFuncAttributeMaxDynamicSharedMemorySize, 131072);
  (void)hipFuncSetAttribute((const void*)attn_kernel,
                            hipFuncAttributeMaxDynamicSharedMemorySize, 131072);

  // workspace layout (126.1 MB, lifetime-based aliasing)
  unsigned short* tk_bf  = (unsigned short*)(ws + 0);
  unsigned short* tv_bf  = (unsigned short*)(ws + 8388608);
  unsigned short* k_bf   = (unsigned short*)(ws + 16777216);
  unsigned short* v_bf   = (unsigned short*)(ws + 25165824);
  unsigned short* g_bf   = (unsigned short*)(ws + 0);         // FFN gate (tk/tv dead)
  unsigned short* op0    = (unsigned short*)(ws + 0);         // attn partial 0 (tk/tv dead)
  unsigned short* q_bf   = (unsigned short*)(ws + 33554432);
  unsigned short* ctx_bf = (unsigned short*)(ws + 50331648);
  unsigned short* u_bf   = (unsigned short*)(ws + 33554432);  // aliases q (dead)
  unsigned short* wq_bf  = (unsigned short*)(ws + 67108864);
  unsigned short* wk_bf  = (unsigned short*)(ws + 71303168);
  unsigned short* wv_bf  = (unsigned short*)(ws + 71434240);
  unsigned short* wo_bf  = (unsigned short*)(ws + 71565312);
  unsigned short* wg_bf  = (unsigned short*)(ws + 75759616);
  unsigned short* wu_bf  = (unsigned short*)(ws + 84148224);
  unsigned short* wd_bf  = (unsigned short*)(ws + 92536832);
  unsigned short* h_bf   = (unsigned short*)(ws + 100925440);
  float2*         ml0    = (float2*)(ws + 100925440);         // h_bf dead during attn
  float2*         ml1    = (float2*)(ws + 100925440 + 262144);
  float*          x2     = (float*)(ws + 109314048);
  unsigned short* op1    = (unsigned short*)(ws + 109314048); // x2 dead until Wo

  dim3 blk(256);
  convert9<<<dim3(24704), blk, 0, stream>>>(
      Wq, Wk, Wv, Wo, Wg, Wu, Wd, tk, tv,
      wq_bf, wk_bf, wv_bf, wo_bf, wg_bf, wu_bf, wd_bf, tk_bf, tv_bf);

  rmsnorm_kernel<<<dim3(4096), blk, 0, stream>>>(x, ln1, h_bf);
  gemm_nt<0, 1><<<dim3(16, 32), blk, 0, stream>>>(h_bf, wq_bf, nullptr, q_bf, 4096, 2048, 1024);
  rope_kernel<<<dim3(16384), blk, 0, stream>>>(q_bf);
  gemm_nt64<0, 1><<<dim3(2, 256), blk, 0, stream>>>(tk_bf, wk_bf, nullptr, k_bf, 16384, 256, 256);
  gemm_nt64<0, 1><<<dim3(2, 256), blk, 0, stream>>>(tv_bf, wv_bf, nullptr, v_bf, 16384, 256, 256);
  attn_kernel<<<dim3(4, 8, 16), dim3(512), 131072, stream>>>(q_bf, k_bf, v_bf, op0, op1, ml0, ml1);
  attn_merge<<<dim3(4096), blk, 0, stream>>>(op0, op1, ml0, ml1, ctx_bf);
  gemm_nt64<1, 0><<<dim3(8, 64), blk, 0, stream>>>(ctx_bf, wo_bf, x, x2, 4096, 1024, 2048);
  rmsnorm_kernel<<<dim3(4096), blk, 0, stream>>>(x2, ln2, h_bf);
  gemm256<0><<<dim3(16, 16), dim3(512), 131072, stream>>>(h_bf, wg_bf, nullptr, g_bf, 4096, 4096, 1024);
  gemm256<1><<<dim3(16, 16), dim3(512), 131072, stream>>>(h_bf, wu_bf, g_bf, g_bf, 4096, 4096, 1024);
  gemm_nt64<1, 0><<<dim3(8, 64), blk, 0, stream>>>(g_bf, wd_bf, x2, out, 4096, 1024, 4096);
}